// Round 1
// baseline (245.504 us; speedup 1.0000x reference)
//
#include <hip/hip_runtime.h>

// Fused grouped 4-layer MLP: 64 models × 32768 tokens, d=64, fp32 in/out,
// f16 MFMA (fp32 accumulate) inside.
//
// Orientation: D[f][tok] (A = W rows=features, B = Z^T cols=tokens).
// k-map for BOTH operands: k = 32*kk + 16*(j>>2) + 4*g + (j&3)  (bijection →
// MFMA result independent of HW intra-lane k order). With the verified C/D
// layout (col=lane&15 = token, row = 4*(lane>>4)+reg = feature), the next
// layer's B fragment is a pure in-lane relu+cast repack of the accumulator:
// no LDS, no shuffles, no barriers anywhere.

typedef __attribute__((ext_vector_type(8))) _Float16 f16x8;
typedef __attribute__((ext_vector_type(4))) float f32x4;

#define MODELS 64
#define LAYERS 4
#define DIM 64
#define TOKS_PER_MODEL 32768
#define BLOCKS_PER_MODEL 16
#define WAVES_PER_BLOCK 4
#define TOK_PER_WAVE (TOKS_PER_MODEL / (BLOCKS_PER_MODEL * WAVES_PER_BLOCK)) // 512
#define TILES_PER_WAVE (TOK_PER_WAVE / 16) // 32

static __device__ __forceinline__ unsigned bf16bits(float f) {
    unsigned u = __builtin_bit_cast(unsigned, f);
    return (u + 0x7fffu + ((u >> 16) & 1u)) >> 16; // RNE to bf16 bits
}

__global__ __launch_bounds__(256, 2) void mlp4_fused(
    const float* __restrict__ x, const float* __restrict__ W,
    const float* __restrict__ b, float* __restrict__ out) {

    const int lane = threadIdx.x & 63;
    const int wave = threadIdx.x >> 6;
    const int c = lane & 15;   // token column (B/D) and W feature row (A)
    const int g = lane >> 4;   // k-group

    const int m   = blockIdx.x / BLOCKS_PER_MODEL;
    const int blk = blockIdx.x % BLOCKS_PER_MODEL;
    const size_t tok0 = (size_t)m * TOKS_PER_MODEL
                      + (size_t)(blk * WAVES_PER_BLOCK + wave) * TOK_PER_WAVE;

    // ---- W fragments (A operand), held in registers for the whole wave ----
    // wf[l][t][kk], element j = f16(W[m][l][16t + c][32kk + 16*(j>>2) + 4g + (j&3)])
    f16x8 wf[LAYERS][4][2];
    const float* Wm = W + (size_t)m * LAYERS * DIM * DIM;
    #pragma unroll
    for (int l = 0; l < LAYERS; ++l) {
        #pragma unroll
        for (int t = 0; t < 4; ++t) {
            const float* row = Wm + ((size_t)l * DIM + (t * 16 + c)) * DIM + 4 * g;
            f32x4 c0 = *(const f32x4*)(row + 0);
            f32x4 c1 = *(const f32x4*)(row + 16);
            f32x4 c2 = *(const f32x4*)(row + 32);
            f32x4 c3 = *(const f32x4*)(row + 48);
            f16x8 a0, a1;
            #pragma unroll
            for (int e = 0; e < 4; ++e) {
                a0[e]     = (_Float16)c0[e];
                a0[4 + e] = (_Float16)c1[e];
                a1[e]     = (_Float16)c2[e];
                a1[4 + e] = (_Float16)c3[e];
            }
            wf[l][t][0] = a0;
            wf[l][t][1] = a1;
        }
    }

    // ---- bias, packed 2×bf16 per dword (saves 32 VGPRs; err ~1e-3 ok) ----
    // acc[t][r] bias value is b[m][l][16t + 4g + r]
    unsigned bpk[LAYERS][8];
    const float* bm = b + (size_t)m * LAYERS * DIM;
    #pragma unroll
    for (int l = 0; l < LAYERS; ++l) {
        #pragma unroll
        for (int t = 0; t < 4; ++t) {
            #pragma unroll
            for (int p = 0; p < 2; ++p) {
                unsigned r0 = bf16bits(bm[l * DIM + t * 16 + 4 * g + 2 * p]);
                unsigned r1 = bf16bits(bm[l * DIM + t * 16 + 4 * g + 2 * p + 1]);
                bpk[l][t * 2 + p] = (r1 << 16) | r0;
            }
        }
    }

    // Lane's global base: token (tok0 + c), column offset 4g.
    const float* xp = x   + tok0 * DIM + (size_t)(c * DIM + 4 * g);
    float*       op = out + tok0 * DIM + (size_t)(c * DIM + 4 * g);

    f32x4 xr0 = *(const f32x4*)(xp + 0);
    f32x4 xr1 = *(const f32x4*)(xp + 16);
    f32x4 xr2 = *(const f32x4*)(xp + 32);
    f32x4 xr3 = *(const f32x4*)(xp + 48);

    #pragma unroll 1
    for (int tile = 0; tile < TILES_PER_WAVE; ++tile) {
        // register-double-buffered prefetch of next tile's x
        const int nxt = (tile + 1 < TILES_PER_WAVE) ? (tile + 1) : 0;
        const float* nx = xp + (size_t)nxt * 16 * DIM;
        f32x4 xn0 = *(const f32x4*)(nx + 0);
        f32x4 xn1 = *(const f32x4*)(nx + 16);
        f32x4 xn2 = *(const f32x4*)(nx + 32);
        f32x4 xn3 = *(const f32x4*)(nx + 48);

        // layer-0 B fragments from current x registers
        f16x8 z0, z1;
        #pragma unroll
        for (int e = 0; e < 4; ++e) {
            z0[e]     = (_Float16)xr0[e];
            z0[4 + e] = (_Float16)xr1[e];
            z1[e]     = (_Float16)xr2[e];
            z1[4 + e] = (_Float16)xr3[e];
        }

        f32x4 acc[4];
        #pragma unroll
        for (int l = 0; l < LAYERS; ++l) {
            // init acc with bias (unpack bf16 pairs: <<16 / &hi)
            #pragma unroll
            for (int t = 0; t < 4; ++t) {
                unsigned p0 = bpk[l][t * 2], p1 = bpk[l][t * 2 + 1];
                acc[t][0] = __builtin_bit_cast(float, p0 << 16);
                acc[t][1] = __builtin_bit_cast(float, p0 & 0xffff0000u);
                acc[t][2] = __builtin_bit_cast(float, p1 << 16);
                acc[t][3] = __builtin_bit_cast(float, p1 & 0xffff0000u);
            }
            #pragma unroll
            for (int t = 0; t < 4; ++t)
                acc[t] = __builtin_amdgcn_mfma_f32_16x16x32_f16(wf[l][t][0], z0, acc[t], 0, 0, 0);
            #pragma unroll
            for (int t = 0; t < 4; ++t)
                acc[t] = __builtin_amdgcn_mfma_f32_16x16x32_f16(wf[l][t][1], z1, acc[t], 0, 0, 0);

            if (l < LAYERS - 1) {
                // next-layer B fragment = in-lane relu+cast repack of acc:
                // z[kk][j] = relu(acc[2kk + (j>>2)][j&3])
                f16x8 n0, n1;
                #pragma unroll
                for (int j = 0; j < 8; ++j) {
                    n0[j] = (_Float16)fmaxf(acc[(j >> 2)    ][j & 3], 0.0f);
                    n1[j] = (_Float16)fmaxf(acc[2 + (j >> 2)][j & 3], 0.0f);
                }
                z0 = n0;
                z1 = n1;
            }
        }

        // store: f = 16t + 4g + r → r contiguous → dwordx4 stores
        float* o = op + (size_t)tile * 16 * DIM;
        #pragma unroll
        for (int t = 0; t < 4; ++t) {
            f32x4 res;
            #pragma unroll
            for (int r = 0; r < 4; ++r) res[r] = fmaxf(acc[t][r], 0.0f);
            *(f32x4*)(o + t * 16) = res;
        }

        xr0 = xn0; xr1 = xn1; xr2 = xn2; xr3 = xn3;
    }
}

extern "C" void kernel_launch(void* const* d_in, const int* in_sizes, int n_in,
                              void* d_out, int out_size, void* d_ws, size_t ws_size,
                              hipStream_t stream) {
    (void)in_sizes; (void)n_in; (void)out_size; (void)d_ws; (void)ws_size;
    const float* x = (const float*)d_in[0];
    const float* W = (const float*)d_in[1];
    const float* b = (const float*)d_in[2];
    float* out = (float*)d_out;
    mlp4_fused<<<dim3(MODELS * BLOCKS_PER_MODEL), dim3(256), 0, stream>>>(x, W, b, out);
}